// Round 20
// baseline (138.820 us; speedup 1.0000x reference)
//
#include <hip/hip_runtime.h>
#include <hip/hip_bf16.h>
#include <cstdint>
#include <cstddef>

typedef __attribute__((ext_vector_type(4))) float  f32x4;
typedef __attribute__((ext_vector_type(8))) short  short8;
typedef __attribute__((ext_vector_type(4))) short  short4v;

typedef __attribute__((address_space(3))) uint32_t as3_u32;
typedef __attribute__((address_space(1))) uint32_t as1_u32;

// bf16 RNE via hardware cvt (compiler fuses pairs into v_cvt_pk_bf16_f32)
__device__ __forceinline__ short f2bf(float f) {
  __hip_bfloat16 h = __float2bfloat16(f);
  return *reinterpret_cast<short*>(&h);
}
__device__ __forceinline__ float sigmoidf(float x) {
  return 1.0f / (1.0f + __expf(-x));
}

// ---------------- pool: g[b,c] = mean_s x[b,c,s] -> bf16 --------------------
__global__ __launch_bounds__(256) void pool_kernel(const float* __restrict__ x,
                                                   short* __restrict__ g) {
  __shared__ float sums[784];
  const int tid = threadIdx.x;
  const f32x4* base = (const f32x4*)(x + (size_t)blockIdx.x * (16 * 196));
#pragma unroll
  for (int it = 0; it < 4; ++it) {
    int i = it * 256 + tid;
    if (it < 3 || tid < 16) {
      f32x4 v = base[i];
      sums[i] = v[0] + v[1] + v[2] + v[3];
    }
  }
  __syncthreads();
  if (tid < 16) {
    float s = 0.f;
#pragma unroll
    for (int j = 0; j < 49; ++j) s += sums[tid * 49 + j];
    g[blockIdx.x * 16 + tid] = f2bf(s * (1.0f / 196.0f));
  }
}

// ---------------- cast_w2: f32 -> bf16, pool-shaped streaming ---------------
// 16384 blocks x 256 threads x 8 elems; fully contiguous read+write.
// THE diagnostic: if this streams at ~6 TB/s, G2-shaped readers were the
// problem; if it crawls at ~2 TB/s, the w2 stream is pattern-independent.
__global__ __launch_bounds__(256) void cast_w2_kernel(const float* __restrict__ w2,
                                                      short* __restrict__ w2bf) {
  const size_t g = (size_t)blockIdx.x * 256 + threadIdx.x;
  const float* src = w2 + g * 8;
  f32x4 a = *(const f32x4*)(src);
  f32x4 b = *(const f32x4*)(src + 4);
  short8 o;
  o[0] = f2bf(a[0]); o[1] = f2bf(a[1]); o[2] = f2bf(a[2]); o[3] = f2bf(a[3]);
  o[4] = f2bf(b[0]); o[5] = f2bf(b[1]); o[6] = f2bf(b[2]); o[7] = f2bf(b[3]);
  *(short8*)(w2bf + g * 8) = o;
}

// --------- GEMM1 (R11-proven): 1-deep reg prefetch, 16-wave K-split ---------
template<int N, int K, int WAVES, bool OUT_BF16>
__device__ __forceinline__ void gemm_body(const short* __restrict__ A,
                                          const float* __restrict__ B,
                                          const float* __restrict__ bias,
                                          void* __restrict__ outp,
                                          float* __restrict__ red) {
  constexpr int KW = K / WAVES;
  constexpr int NK = KW / 32;
  constexpr int NT = WAVES * 64;
  const int n0  = blockIdx.x * 16;
  const int tid = threadIdx.x;
  const int l   = tid & 63;
  const int wv  = tid >> 6;
  const int kw0 = wv * KW;

  const int ko = (l >> 4) * 8;
  const float* Bp = B + (size_t)(n0 + (l & 15)) * K + kw0 + ko;
  const short* Ap = A + (size_t)(l & 15) * K + kw0 + ko;

  f32x4 acc0 = {}, acc1 = {}, acc2 = {}, acc3 = {};

  f32x4 bc0 = *(const f32x4*)(Bp);
  f32x4 bc1 = *(const f32x4*)(Bp + 4);
  short8 ac0 = *(const short8*)(Ap);
  short8 ac1 = *(const short8*)(Ap + 16 * K);
  short8 ac2 = *(const short8*)(Ap + 32 * K);
  short8 ac3 = *(const short8*)(Ap + 48 * K);

  for (int t = 0; t < NK; ++t) {
    f32x4 bn0 = {}, bn1 = {};
    short8 an0 = {}, an1 = {}, an2 = {}, an3 = {};
    if (t + 1 < NK) {
      const float* bp = Bp + (t + 1) * 32;
      const short* ap = Ap + (t + 1) * 32;
      bn0 = *(const f32x4*)(bp);
      bn1 = *(const f32x4*)(bp + 4);
      an0 = *(const short8*)(ap);
      an1 = *(const short8*)(ap + 16 * K);
      an2 = *(const short8*)(ap + 32 * K);
      an3 = *(const short8*)(ap + 48 * K);
    }
    short8 bb;
    bb[0] = f2bf(bc0[0]); bb[1] = f2bf(bc0[1]); bb[2] = f2bf(bc0[2]); bb[3] = f2bf(bc0[3]);
    bb[4] = f2bf(bc1[0]); bb[5] = f2bf(bc1[1]); bb[6] = f2bf(bc1[2]); bb[7] = f2bf(bc1[3]);
    acc0 = __builtin_amdgcn_mfma_f32_16x16x32_bf16(ac0, bb, acc0, 0, 0, 0);
    acc1 = __builtin_amdgcn_mfma_f32_16x16x32_bf16(ac1, bb, acc1, 0, 0, 0);
    acc2 = __builtin_amdgcn_mfma_f32_16x16x32_bf16(ac2, bb, acc2, 0, 0, 0);
    acc3 = __builtin_amdgcn_mfma_f32_16x16x32_bf16(ac3, bb, acc3, 0, 0, 0);
    bc0 = bn0; bc1 = bn1;
    ac0 = an0; ac1 = an1; ac2 = an2; ac3 = an3;
  }

  {
    float* rw = red + wv * 1024;
    const int mb = (l >> 4) << 2;
    const int nn = l & 15;
#pragma unroll
    for (int r = 0; r < 4; ++r) rw[(0  + mb + r) * 16 + nn] = acc0[r];
#pragma unroll
    for (int r = 0; r < 4; ++r) rw[(16 + mb + r) * 16 + nn] = acc1[r];
#pragma unroll
    for (int r = 0; r < 4; ++r) rw[(32 + mb + r) * 16 + nn] = acc2[r];
#pragma unroll
    for (int r = 0; r < 4; ++r) rw[(48 + mb + r) * 16 + nn] = acc3[r];
  }
  __syncthreads();

#pragma unroll
  for (int i = tid; i < 1024; i += NT) {
    float s = 0.f;
#pragma unroll
    for (int w = 0; w < WAVES; ++w) s += red[w * 1024 + i];
    int m  = i >> 4;
    int nn = n0 + (i & 15);
    s = sigmoidf(s + bias[nn]);
    if constexpr (OUT_BF16) ((short*)outp)[(size_t)m * N + nn] = f2bf(s);
    else                    ((float*)outp)[(size_t)m * N + nn] = s;
  }
}

// GEMM1: 16 waves (1024 threads), 256 blocks -> 16 waves/CU
__global__ __launch_bounds__(1024, 4) void gemm1_kernel(const short* __restrict__ A,
                                                        const float* __restrict__ B,
                                                        const float* __restrict__ bias,
                                                        short* __restrict__ outp) {
  __shared__ float red[16 * 1024];
  gemm_body<4096, 2048, 16, true>(A, B, bias, outp, red);
}

// --------- GEMM2 (bf16 B): counted-vmcnt 3-ring, L3-resident w2bf -----------
// 512 blocks x 8 waves; n-tile = 16 rows of w2bf (row stride 8 KB).
// K in 8 chunks of 512 k (16 KB bf16). Ring 3 x 16 KB (48 KB -> 3 blocks/CU).
// Per iter: wait vmcnt(10) [s(c) done; A(c)[8] + s(c+1)[2] in flight],
// barrier, A(c+1)[8], s(c+2)[2], compute 2 MFMA-steps from LDS (no cvt).
__global__ __launch_bounds__(512, 6) void gemm2_bf16(const short* __restrict__ A,
                                                     const short* __restrict__ Bbf,
                                                     const float* __restrict__ bias,
                                                     float* __restrict__ outp,
                                                     float* __restrict__ zbuf) {
  constexpr int N = 8192, K = 4096;
  __shared__ char ldsb[49152];          // 3 x 16 KB ring (re-used as red[])
  const int tid = threadIdx.x;
  const int l   = tid & 63;
  const int wv  = tid >> 6;
  const int n0  = blockIdx.x * 16;

  if (tid < 98) zbuf[blockIdx.x * 98 + tid] = 0.f;

  const char*  gB = (const char*)Bbf + (size_t)n0 * (K * 2);  // 8 KB per row
  const short* Ap = A + (size_t)(l & 15) * K + ((l >> 4) << 3);

#define G2B_STAGE(c_, b_)                                                      \
  {                                                                            \
    _Pragma("unroll")                                                          \
    for (int j = 0; j < 2; ++j) {                                              \
      int idx = j * 512 + tid;                                                 \
      int r   = idx >> 6;                                                      \
      int d   = (idx & 63) << 4;                                               \
      int s   = d ^ ((r & 7) << 4);                                            \
      const char* src = gB + (size_t)r * (K * 2) + (size_t)(c_) * 1024 + s;    \
      char* dst = (char*)ldsb + (size_t)(b_) * 16384 +                         \
                  (size_t)(j * 512 + (tid & ~63)) * 16;                        \
      __builtin_amdgcn_global_load_lds((as1_u32*)src, (as3_u32*)dst, 16, 0, 0);\
    }                                                                          \
  }
#define G2B_LOADA(c_, ar_)                                                     \
  {                                                                            \
    const short* ap = Ap + (c_) * 512 + wv * 64;                               \
    _Pragma("unroll")                                                          \
    for (int t = 0; t < 2; ++t) {                                              \
      _Pragma("unroll")                                                        \
      for (int f = 0; f < 4; ++f)                                              \
        ar_[t * 4 + f] = *(const short8*)(ap + t * 32 + (size_t)f * 16 * K);   \
    }                                                                          \
  }

  f32x4 acc0 = {}, acc1 = {}, acc2 = {}, acc3 = {};
  short8 aC[8], aN[8];

  // prologue: s0[2], A0[8], s1[2]
  G2B_STAGE(0, 0);
  __builtin_amdgcn_sched_barrier(0);
  G2B_LOADA(0, aC);
  __builtin_amdgcn_sched_barrier(0);
  G2B_STAGE(1, 1);
  __builtin_amdgcn_sched_barrier(0);

  const int row = l & 15;
  const int swz = (row & 7) << 4;
  const int rb  = row * 1024;

  int s0i = 0, s1i = 1, s2i = 2;

#pragma unroll 1
  for (int c = 0; c < 8; ++c) {
    if (c < 7) { asm volatile("s_waitcnt vmcnt(10)" ::: "memory"); }
    else       { asm volatile("s_waitcnt vmcnt(8)"  ::: "memory"); }
    __builtin_amdgcn_sched_barrier(0);
    __builtin_amdgcn_s_barrier();
    __builtin_amdgcn_sched_barrier(0);
    if (c + 1 < 8) { G2B_LOADA(c + 1, aN); }
    __builtin_amdgcn_sched_barrier(0);
    if (c + 2 < 8) { G2B_STAGE(c + 2, s2i); }
    __builtin_amdgcn_sched_barrier(0);

    const char* bufc = ldsb + (size_t)s0i * 16384;
#pragma unroll
    for (int t = 0; t < 2; ++t) {
      const int kb = (wv << 7) + (t << 6) + ((l >> 4) << 4);
      short8 bb = *(const short8*)(bufc + rb + (kb ^ swz));
      acc0 = __builtin_amdgcn_mfma_f32_16x16x32_bf16(aC[t * 4 + 0], bb, acc0, 0, 0, 0);
      acc1 = __builtin_amdgcn_mfma_f32_16x16x32_bf16(aC[t * 4 + 1], bb, acc1, 0, 0, 0);
      acc2 = __builtin_amdgcn_mfma_f32_16x16x32_bf16(aC[t * 4 + 2], bb, acc2, 0, 0, 0);
      acc3 = __builtin_amdgcn_mfma_f32_16x16x32_bf16(aC[t * 4 + 3], bb, acc3, 0, 0, 0);
    }

    if (c + 1 < 8) {
#pragma unroll
      for (int f = 0; f < 8; ++f) aC[f] = aN[f];
    }
    int t2 = s0i; s0i = s1i; s1i = s2i; s2i = t2;
  }

  // epilogue: reuse LDS as red[8][1024]
  __syncthreads();
  float* red = (float*)ldsb;
  {
    float* rw = red + wv * 1024;
    const int mb = (l >> 4) << 2;
    const int nn = l & 15;
#pragma unroll
    for (int r = 0; r < 4; ++r) rw[(0  + mb + r) * 16 + nn] = acc0[r];
#pragma unroll
    for (int r = 0; r < 4; ++r) rw[(16 + mb + r) * 16 + nn] = acc1[r];
#pragma unroll
    for (int r = 0; r < 4; ++r) rw[(32 + mb + r) * 16 + nn] = acc2[r];
#pragma unroll
    for (int r = 0; r < 4; ++r) rw[(48 + mb + r) * 16 + nn] = acc3[r];
  }
  __syncthreads();
#pragma unroll
  for (int i = tid; i < 1024; i += 512) {
    float s = 0.f;
#pragma unroll
    for (int w = 0; w < 8; ++w) s += red[w * 1024 + i];
    int m  = i >> 4;
    int nn = n0 + (i & 15);
    outp[(size_t)m * N + nn] = sigmoidf(s + bias[nn]);
  }
#undef G2B_STAGE
#undef G2B_LOADA
}

// --------- GEMM2 fallback (f32 B): exact R17 counted-vmcnt ring -------------
__global__ __launch_bounds__(512, 6) void gemm2_f32(const short* __restrict__ A,
                                                    const float* __restrict__ B,
                                                    const float* __restrict__ bias,
                                                    float* __restrict__ outp,
                                                    float* __restrict__ zbuf) {
  constexpr int N = 8192, K = 4096;
  __shared__ float lds[12288];
  const int tid = threadIdx.x;
  const int l   = tid & 63;
  const int wv  = tid >> 6;
  const int n0  = blockIdx.x * 16;

  if (tid < 98) zbuf[blockIdx.x * 98 + tid] = 0.f;

  const char*  gB = (const char*)B + (size_t)n0 * (K * 4);
  const short* Ap = A + (size_t)(l & 15) * K + ((l >> 4) << 3);

#define G2_STAGE(c_, b_)                                                       \
  {                                                                            \
    _Pragma("unroll")                                                          \
    for (int j = 0; j < 2; ++j) {                                              \
      int idx = j * 512 + tid;                                                 \
      int r   = idx >> 6;                                                      \
      int d   = (idx & 63) << 4;                                               \
      int s   = d ^ ((r & 7) << 4);                                            \
      const char* src = gB + (size_t)r * (K * 4) + (size_t)(c_) * 1024 + s;    \
      char* dst = (char*)lds + (size_t)(b_) * 16384 +                          \
                  (size_t)(j * 512 + (tid & ~63)) * 16;                        \
      __builtin_amdgcn_global_load_lds((as1_u32*)src, (as3_u32*)dst, 16, 0, 0);\
    }                                                                          \
  }
#define G2_LOADA(c_, ar_)                                                      \
  {                                                                            \
    const short* ap = Ap + (c_) * 256 + wv * 32;                               \
    _Pragma("unroll")                                                          \
    for (int f = 0; f < 4; ++f)                                                \
      ar_[f] = *(const short8*)(ap + (size_t)f * 16 * K);                      \
  }

  f32x4 acc0 = {}, acc1 = {}, acc2 = {}, acc3 = {};
  short8 aC[4], aN[4];

  G2_STAGE(0, 0);
  __builtin_amdgcn_sched_barrier(0);
  G2_LOADA(0, aC);
  __builtin_amdgcn_sched_barrier(0);
  G2_STAGE(1, 1);
  __builtin_amdgcn_sched_barrier(0);

  const int row = l & 15;
  const int swz = (row & 7) << 4;
  const int rb  = row * 1024;
  const int kb  = (wv << 7) + ((l >> 4) << 5);

  int s0i = 0, s1i = 1, s2i = 2;

#pragma unroll 1
  for (int c = 0; c < 16; ++c) {
    if (c < 15) { asm volatile("s_waitcnt vmcnt(6)" ::: "memory"); }
    else        { asm volatile("s_waitcnt vmcnt(4)" ::: "memory"); }
    __builtin_amdgcn_sched_barrier(0);
    __builtin_amdgcn_s_barrier();
    __builtin_amdgcn_sched_barrier(0);
    if (c + 1 < 16) { G2_LOADA(c + 1, aN); }
    __builtin_amdgcn_sched_barrier(0);
    if (c + 2 < 16) { G2_STAGE(c + 2, s2i); }
    __builtin_amdgcn_sched_barrier(0);

    const char* bufc = (const char*)lds + (size_t)s0i * 16384;
    f32x4 b0 = *(const f32x4*)(bufc + rb + ((kb)      ^ swz));
    f32x4 b1 = *(const f32x4*)(bufc + rb + ((kb + 16) ^ swz));
    short8 bb;
    bb[0] = f2bf(b0[0]); bb[1] = f2bf(b0[1]); bb[2] = f2bf(b0[2]); bb[3] = f2bf(b0[3]);
    bb[4] = f2bf(b1[0]); bb[5] = f2bf(b1[1]); bb[6] = f2bf(b1[2]); bb[7] = f2bf(b1[3]);
    acc0 = __builtin_amdgcn_mfma_f32_16x16x32_bf16(aC[0], bb, acc0, 0, 0, 0);
    acc1 = __builtin_amdgcn_mfma_f32_16x16x32_bf16(aC[1], bb, acc1, 0, 0, 0);
    acc2 = __builtin_amdgcn_mfma_f32_16x16x32_bf16(aC[2], bb, acc2, 0, 0, 0);
    acc3 = __builtin_amdgcn_mfma_f32_16x16x32_bf16(aC[3], bb, acc3, 0, 0, 0);

    if (c + 1 < 16) {
#pragma unroll
      for (int f = 0; f < 4; ++f) aC[f] = aN[f];
    }
    int t = s0i; s0i = s1i; s1i = s2i; s2i = t;
  }

  __syncthreads();
  float* red = lds;
  {
    float* rw = red + wv * 1024;
    const int mb = (l >> 4) << 2;
    const int nn = l & 15;
#pragma unroll
    for (int r = 0; r < 4; ++r) rw[(0  + mb + r) * 16 + nn] = acc0[r];
#pragma unroll
    for (int r = 0; r < 4; ++r) rw[(16 + mb + r) * 16 + nn] = acc1[r];
#pragma unroll
    for (int r = 0; r < 4; ++r) rw[(32 + mb + r) * 16 + nn] = acc2[r];
#pragma unroll
    for (int r = 0; r < 4; ++r) rw[(48 + mb + r) * 16 + nn] = acc3[r];
  }
  __syncthreads();
#pragma unroll
  for (int i = tid; i < 1024; i += 512) {
    float s = 0.f;
#pragma unroll
    for (int w = 0; w < 8; ++w) s += red[w * 1024 + i];
    int m  = i >> 4;
    int nn = n0 + (i & 15);
    outp[(size_t)m * N + nn] = sigmoidf(s + bias[nn]);
  }
#undef G2_STAGE
#undef G2_LOADA
}

// --------- einsum: feat[b,p,s] += (1/C) sum_{c in chunk} w[b,p,c] x[b,c,s] --
__global__ __launch_bounds__(256) void einsum_kernel(const float* __restrict__ x,
                                                     const float* __restrict__ wg,
                                                     float* __restrict__ feat) {
  const int b   = blockIdx.x >> 4;
  const int cc  = blockIdx.x & 15;
  const int tid = threadIdx.x;
  if (tid >= 196) return;
  const float* wp = wg + (size_t)b * 8192 + cc * 128;
  const float* xp = x + (size_t)b * 2048 * 196 + (size_t)cc * 128 * 196 + tid;
  float a0 = 0.f, a1 = 0.f, a2 = 0.f, a3 = 0.f;
#pragma unroll 8
  for (int c = 0; c < 128; ++c) {
    float xv = xp[(size_t)c * 196];
    a0 = __builtin_fmaf(wp[c],        xv, a0);
    a1 = __builtin_fmaf(wp[2048 + c], xv, a1);
    a2 = __builtin_fmaf(wp[4096 + c], xv, a2);
    a3 = __builtin_fmaf(wp[6144 + c], xv, a3);
  }
  const float invC = 1.0f / 2048.0f;
  atomicAdd(feat + (b * 4 + 0) * 196 + tid, a0 * invC);
  atomicAdd(feat + (b * 4 + 1) * 196 + tid, a1 * invC);
  atomicAdd(feat + (b * 4 + 2) * 196 + tid, a2 * invC);
  atomicAdd(feat + (b * 4 + 3) * 196 + tid, a3 * invC);
}

extern "C" void kernel_launch(void* const* d_in, const int* in_sizes, int n_in,
                              void* d_out, int out_size, void* d_ws, size_t ws_size,
                              hipStream_t stream) {
  const float* x  = (const float*)d_in[0];   // [64,2048,14,14]
  const float* w1 = (const float*)d_in[1];   // [4096,2048]
  const float* b1 = (const float*)d_in[2];   // [4096]
  const float* w2 = (const float*)d_in[3];   // [8192,4096]
  const float* b2 = (const float*)d_in[4];   // [8192]
  float* out = (float*)d_out;

  short* g_bf  = (short*)d_ws;                       // 64*2048 bf16 (256 KB)
  short* h_bf  = g_bf + 64 * 2048;                   // 64*4096 bf16 (512 KB)
  short* w2_bf = (short*)((char*)d_ws + (1 << 20));  // 8192*4096 bf16 (64 MB)

  const bool use_cast = ws_size >= ((size_t)(1 << 20) + 67108864ULL);

  float* wout = out;                         // [64, 8192] == [B,P,C] flat
  float* feat = out + 524288;                // [64, 4, 196]

  // 1) pool -> g (bf16)
  pool_kernel<<<(64 * 2048) / 16, 256, 0, stream>>>(x, g_bf);

  // 2) GEMM1: h = sigmoid(g @ w1^T + b1), bf16 out
  gemm1_kernel<<<4096 / 16, 1024, 0, stream>>>(g_bf, w1, b1, h_bf);

  if (use_cast) {
    // 3a) cast w2 -> bf16 (pool-shaped contiguous stream; the diagnostic)
    cast_w2_kernel<<<16384, 256, 0, stream>>>(w2, w2_bf);
    // 3b) GEMM2 on L3-resident bf16 weights
    gemm2_bf16<<<512, 512, 0, stream>>>(h_bf, w2_bf, b2, wout, feat);
  } else {
    // fallback: R17 f32 ring
    gemm2_f32<<<512, 512, 0, stream>>>(h_bf, w2, b2, wout, feat);
  }

  // 4) einsum -> feat (atomic accumulate over 16 c-chunks)
  einsum_kernel<<<64 * 16, 256, 0, stream>>>(x, wout, feat);
}

// Round 21
// 94.113 us; speedup vs baseline: 1.4750x; 1.4750x over previous
//
#include <hip/hip_runtime.h>
#include <hip/hip_bf16.h>
#include <cstdint>
#include <cstddef>

// FINAL MODEL (R20 post-mortem): this pipeline is bound by the measured
// HBM streaming-READ rate of ~3.0-3.3 TB/s (writes: 7.1; L3 hits: fast).
// G2 at ~44 us = 134 MB / 3.05 TB/s is AT that wall; floor = 198 MB HBM
// reads @3.2 + ~25 us L3 passes + gaps = ~93 us. This kernel: 95.0.

typedef __attribute__((ext_vector_type(4))) float  f32x4;
typedef __attribute__((ext_vector_type(8))) short  short8;

typedef __attribute__((address_space(3))) uint32_t as3_u32;
typedef __attribute__((address_space(1))) uint32_t as1_u32;

__device__ __forceinline__ short f2bf(float f) {
  __hip_bfloat16 h = __float2bfloat16(f);
  return *reinterpret_cast<short*>(&h);
}
__device__ __forceinline__ float sigmoidf(float x) {
  return 1.0f / (1.0f + __expf(-x));
}

// ---------------- pool: g[b,c] = mean_s x[b,c,s] -> bf16 --------------------
__global__ __launch_bounds__(256) void pool_kernel(const float* __restrict__ x,
                                                   short* __restrict__ g) {
  __shared__ float sums[784];
  const int tid = threadIdx.x;
  const f32x4* base = (const f32x4*)(x + (size_t)blockIdx.x * (16 * 196));
#pragma unroll
  for (int it = 0; it < 4; ++it) {
    int i = it * 256 + tid;
    if (it < 3 || tid < 16) {
      f32x4 v = base[i];
      sums[i] = v[0] + v[1] + v[2] + v[3];
    }
  }
  __syncthreads();
  if (tid < 16) {
    float s = 0.f;
#pragma unroll
    for (int j = 0; j < 49; ++j) s += sums[tid * 49 + j];
    g[blockIdx.x * 16 + tid] = f2bf(s * (1.0f / 196.0f));
  }
}

// --------- GEMM1 (R11-proven): 1-deep reg prefetch, 16-wave K-split ---------
template<int N, int K, int WAVES, bool OUT_BF16>
__device__ __forceinline__ void gemm_body(const short* __restrict__ A,
                                          const float* __restrict__ B,
                                          const float* __restrict__ bias,
                                          void* __restrict__ outp,
                                          float* __restrict__ red) {
  constexpr int KW = K / WAVES;
  constexpr int NK = KW / 32;
  constexpr int NT = WAVES * 64;
  const int n0  = blockIdx.x * 16;
  const int tid = threadIdx.x;
  const int l   = tid & 63;
  const int wv  = tid >> 6;
  const int kw0 = wv * KW;

  const int ko = (l >> 4) * 8;
  const float* Bp = B + (size_t)(n0 + (l & 15)) * K + kw0 + ko;
  const short* Ap = A + (size_t)(l & 15) * K + kw0 + ko;

  f32x4 acc0 = {}, acc1 = {}, acc2 = {}, acc3 = {};

  f32x4 bc0 = *(const f32x4*)(Bp);
  f32x4 bc1 = *(const f32x4*)(Bp + 4);
  short8 ac0 = *(const short8*)(Ap);
  short8 ac1 = *(const short8*)(Ap + 16 * K);
  short8 ac2 = *(const short8*)(Ap + 32 * K);
  short8 ac3 = *(const short8*)(Ap + 48 * K);

  for (int t = 0; t < NK; ++t) {
    f32x4 bn0 = {}, bn1 = {};
    short8 an0 = {}, an1 = {}, an2 = {}, an3 = {};
    if (t + 1 < NK) {
      const float* bp = Bp + (t + 1) * 32;
      const short* ap = Ap + (t + 1) * 32;
      bn0 = *(const f32x4*)(bp);
      bn1 = *(const f32x4*)(bp + 4);
      an0 = *(const short8*)(ap);
      an1 = *(const short8*)(ap + 16 * K);
      an2 = *(const short8*)(ap + 32 * K);
      an3 = *(const short8*)(ap + 48 * K);
    }
    short8 bb;
    bb[0] = f2bf(bc0[0]); bb[1] = f2bf(bc0[1]); bb[2] = f2bf(bc0[2]); bb[3] = f2bf(bc0[3]);
    bb[4] = f2bf(bc1[0]); bb[5] = f2bf(bc1[1]); bb[6] = f2bf(bc1[2]); bb[7] = f2bf(bc1[3]);
    acc0 = __builtin_amdgcn_mfma_f32_16x16x32_bf16(ac0, bb, acc0, 0, 0, 0);
    acc1 = __builtin_amdgcn_mfma_f32_16x16x32_bf16(ac1, bb, acc1, 0, 0, 0);
    acc2 = __builtin_amdgcn_mfma_f32_16x16x32_bf16(ac2, bb, acc2, 0, 0, 0);
    acc3 = __builtin_amdgcn_mfma_f32_16x16x32_bf16(ac3, bb, acc3, 0, 0, 0);
    bc0 = bn0; bc1 = bn1;
    ac0 = an0; ac1 = an1; ac2 = an2; ac3 = an3;
  }

  {
    float* rw = red + wv * 1024;
    const int mb = (l >> 4) << 2;
    const int nn = l & 15;
#pragma unroll
    for (int r = 0; r < 4; ++r) rw[(0  + mb + r) * 16 + nn] = acc0[r];
#pragma unroll
    for (int r = 0; r < 4; ++r) rw[(16 + mb + r) * 16 + nn] = acc1[r];
#pragma unroll
    for (int r = 0; r < 4; ++r) rw[(32 + mb + r) * 16 + nn] = acc2[r];
#pragma unroll
    for (int r = 0; r < 4; ++r) rw[(48 + mb + r) * 16 + nn] = acc3[r];
  }
  __syncthreads();

#pragma unroll
  for (int i = tid; i < 1024; i += NT) {
    float s = 0.f;
#pragma unroll
    for (int w = 0; w < WAVES; ++w) s += red[w * 1024 + i];
    int m  = i >> 4;
    int nn = n0 + (i & 15);
    s = sigmoidf(s + bias[nn]);
    if constexpr (OUT_BF16) ((short*)outp)[(size_t)m * N + nn] = f2bf(s);
    else                    ((float*)outp)[(size_t)m * N + nn] = s;
  }
}

// GEMM1: 16 waves (1024 threads), 256 blocks -> 16 waves/CU
__global__ __launch_bounds__(1024, 4) void gemm1_kernel(const short* __restrict__ A,
                                                        const float* __restrict__ B,
                                                        const float* __restrict__ bias,
                                                        short* __restrict__ outp) {
  __shared__ float red[16 * 1024];
  gemm_body<4096, 2048, 16, true>(A, B, bias, outp, red);
}

// --------- GEMM2: counted-vmcnt 3-buffer ring (T4), 3 blocks/CU -------------
// 512 blocks x 8 waves; n-tile = 16 w2-rows; K in 16 chunks of 256 f32 (16 KB).
// Ring of 3 LDS buffers (48 KB). Stage 2 chunks ahead; per-iter s_barrier +
// s_waitcnt vmcnt(6) (never drains to 0 in the loop). At the measured
// ~3.05 TB/s HBM read rate this kernel IS bandwidth-floor (134 MB ~= 44 us).
__global__ __launch_bounds__(512, 6) void gemm2_kernel(const short* __restrict__ A,
                                                       const float* __restrict__ B,
                                                       const float* __restrict__ bias,
                                                       float* __restrict__ outp,
                                                       float* __restrict__ zbuf) {
  constexpr int N = 8192, K = 4096;
  __shared__ float lds[12288];          // 48 KB: 3 x 16 KB ring
  const int tid = threadIdx.x;
  const int l   = tid & 63;
  const int wv  = tid >> 6;
  const int n0  = blockIdx.x * 16;

  // zero feat for einsum's atomics (512 blocks x 98 = 50176 floats)
  if (tid < 98) zbuf[blockIdx.x * 98 + tid] = 0.f;

  const char*  gB = (const char*)B + (size_t)n0 * (K * 4);
  const short* Ap = A + (size_t)(l & 15) * K + ((l >> 4) << 3);

#define G2_STAGE(c_, b_)                                                       \
  {                                                                            \
    _Pragma("unroll")                                                          \
    for (int j = 0; j < 2; ++j) {                                              \
      int idx = j * 512 + tid;                                                 \
      int r   = idx >> 6;                                                      \
      int d   = (idx & 63) << 4;                                               \
      int s   = d ^ ((r & 7) << 4);                                            \
      const char* src = gB + (size_t)r * (K * 4) + (size_t)(c_) * 1024 + s;    \
      char* dst = (char*)lds + (size_t)(b_) * 16384 +                          \
                  (size_t)(j * 512 + (tid & ~63)) * 16;                        \
      __builtin_amdgcn_global_load_lds((as1_u32*)src, (as3_u32*)dst, 16, 0, 0);\
    }                                                                          \
  }
#define G2_LOADA(c_, ar_)                                                      \
  {                                                                            \
    const short* ap = Ap + (c_) * 256 + wv * 32;                               \
    _Pragma("unroll")                                                          \
    for (int f = 0; f < 4; ++f)                                                \
      ar_[f] = *(const short8*)(ap + (size_t)f * 16 * K);                      \
  }

  f32x4 acc0 = {}, acc1 = {}, acc2 = {}, acc3 = {};
  short8 aC[4], aN[4];

  // prologue: s0, A0, s1  (order matters for vmcnt counts)
  G2_STAGE(0, 0);
  __builtin_amdgcn_sched_barrier(0);
  G2_LOADA(0, aC);
  __builtin_amdgcn_sched_barrier(0);
  G2_STAGE(1, 1);
  __builtin_amdgcn_sched_barrier(0);

  const int row = l & 15;
  const int swz = (row & 7) << 4;
  const int rb  = row * 1024;
  const int kb  = (wv << 7) + ((l >> 4) << 5);

  int s0i = 0, s1i = 1, s2i = 2;

#pragma unroll 1
  for (int c = 0; c < 16; ++c) {
    if (c < 15) { asm volatile("s_waitcnt vmcnt(6)" ::: "memory"); }
    else        { asm volatile("s_waitcnt vmcnt(4)" ::: "memory"); }
    __builtin_amdgcn_sched_barrier(0);
    __builtin_amdgcn_s_barrier();
    __builtin_amdgcn_sched_barrier(0);
    if (c + 1 < 16) { G2_LOADA(c + 1, aN); }
    __builtin_amdgcn_sched_barrier(0);
    if (c + 2 < 16) { G2_STAGE(c + 2, s2i); }
    __builtin_amdgcn_sched_barrier(0);

    const char* bufc = (const char*)lds + (size_t)s0i * 16384;
    f32x4 b0 = *(const f32x4*)(bufc + rb + ((kb)      ^ swz));
    f32x4 b1 = *(const f32x4*)(bufc + rb + ((kb + 16) ^ swz));
    short8 bb;
    bb[0] = f2bf(b0[0]); bb[1] = f2bf(b0[1]); bb[2] = f2bf(b0[2]); bb[3] = f2bf(b0[3]);
    bb[4] = f2bf(b1[0]); bb[5] = f2bf(b1[1]); bb[6] = f2bf(b1[2]); bb[7] = f2bf(b1[3]);
    acc0 = __builtin_amdgcn_mfma_f32_16x16x32_bf16(aC[0], bb, acc0, 0, 0, 0);
    acc1 = __builtin_amdgcn_mfma_f32_16x16x32_bf16(aC[1], bb, acc1, 0, 0, 0);
    acc2 = __builtin_amdgcn_mfma_f32_16x16x32_bf16(aC[2], bb, acc2, 0, 0, 0);
    acc3 = __builtin_amdgcn_mfma_f32_16x16x32_bf16(aC[3], bb, acc3, 0, 0, 0);

    if (c + 1 < 16) {
#pragma unroll
      for (int f = 0; f < 4; ++f) aC[f] = aN[f];
    }
    int t = s0i; s0i = s1i; s1i = s2i; s2i = t;
  }

  // epilogue: reuse LDS as red[8][1024]
  __syncthreads();
  float* red = lds;
  {
    float* rw = red + wv * 1024;
    const int mb = (l >> 4) << 2;
    const int nn = l & 15;
#pragma unroll
    for (int r = 0; r < 4; ++r) rw[(0  + mb + r) * 16 + nn] = acc0[r];
#pragma unroll
    for (int r = 0; r < 4; ++r) rw[(16 + mb + r) * 16 + nn] = acc1[r];
#pragma unroll
    for (int r = 0; r < 4; ++r) rw[(32 + mb + r) * 16 + nn] = acc2[r];
#pragma unroll
    for (int r = 0; r < 4; ++r) rw[(48 + mb + r) * 16 + nn] = acc3[r];
  }
  __syncthreads();
#pragma unroll
  for (int i = tid; i < 1024; i += 512) {
    float s = 0.f;
#pragma unroll
    for (int w = 0; w < 8; ++w) s += red[w * 1024 + i];
    int m  = i >> 4;
    int nn = n0 + (i & 15);
    outp[(size_t)m * N + nn] = sigmoidf(s + bias[nn]);
  }
#undef G2_STAGE
#undef G2_LOADA
}

// --------- einsum: feat[b,p,s] += (1/C) sum_{c in chunk} w[b,p,c] x[b,c,s] --
__global__ __launch_bounds__(256) void einsum_kernel(const float* __restrict__ x,
                                                     const float* __restrict__ wg,
                                                     float* __restrict__ feat) {
  const int b   = blockIdx.x >> 4;
  const int cc  = blockIdx.x & 15;
  const int tid = threadIdx.x;
  if (tid >= 196) return;
  const float* wp = wg + (size_t)b * 8192 + cc * 128;
  const float* xp = x + (size_t)b * 2048 * 196 + (size_t)cc * 128 * 196 + tid;
  float a0 = 0.f, a1 = 0.f, a2 = 0.f, a3 = 0.f;
#pragma unroll 8
  for (int c = 0; c < 128; ++c) {
    float xv = xp[(size_t)c * 196];
    a0 = __builtin_fmaf(wp[c],        xv, a0);
    a1 = __builtin_fmaf(wp[2048 + c], xv, a1);
    a2 = __builtin_fmaf(wp[4096 + c], xv, a2);
    a3 = __builtin_fmaf(wp[6144 + c], xv, a3);
  }
  const float invC = 1.0f / 2048.0f;
  atomicAdd(feat + (b * 4 + 0) * 196 + tid, a0 * invC);
  atomicAdd(feat + (b * 4 + 1) * 196 + tid, a1 * invC);
  atomicAdd(feat + (b * 4 + 2) * 196 + tid, a2 * invC);
  atomicAdd(feat + (b * 4 + 3) * 196 + tid, a3 * invC);
}

extern "C" void kernel_launch(void* const* d_in, const int* in_sizes, int n_in,
                              void* d_out, int out_size, void* d_ws, size_t ws_size,
                              hipStream_t stream) {
  const float* x  = (const float*)d_in[0];   // [64,2048,14,14]
  const float* w1 = (const float*)d_in[1];   // [4096,2048]
  const float* b1 = (const float*)d_in[2];   // [4096]
  const float* w2 = (const float*)d_in[3];   // [8192,4096]
  const float* b2 = (const float*)d_in[4];   // [8192]
  float* out = (float*)d_out;

  short* g_bf = (short*)d_ws;                // 64*2048 bf16 (256 KB)
  short* h_bf = g_bf + 64 * 2048;            // 64*4096 bf16 (512 KB)

  float* wout = out;                         // [64, 8192] == [B,P,C] flat
  float* feat = out + 524288;                // [64, 4, 196]

  // 1) pool -> g (bf16): 8192 blocks x 16 rows
  pool_kernel<<<(64 * 2048) / 16, 256, 0, stream>>>(x, g_bf);

  // 2) GEMM1: h = sigmoid(g @ w1^T + b1), bf16 out (256 blocks x 16 waves)
  gemm1_kernel<<<4096 / 16, 1024, 0, stream>>>(g_bf, w1, b1, h_bf);

  // 3) GEMM2: counted-vmcnt ring; w = sigmoid(h @ w2^T + b2); zeroes feat
  gemm2_kernel<<<512, 512, 0, stream>>>(h_bf, w2, b2, wout, feat);

  // 4) einsum -> feat (atomic accumulate over 16 c-chunks)
  einsum_kernel<<<64 * 16, 256, 0, stream>>>(x, wout, feat);
}